// Round 14
// baseline (361.625 us; speedup 1.0000x reference)
//
#include <hip/hip_runtime.h>
#include <cstdint>

#define HS 62
#define HX 248
#define HXW (HX * HX)  // 61504
#define HSW (HS * HS)  // 3844

typedef __attribute__((ext_vector_type(8))) short bf16x8;
typedef __attribute__((ext_vector_type(4))) float f32x4;

static __device__ __forceinline__ unsigned short f2bf(float f) {
  uint32_t u = __builtin_bit_cast(uint32_t, f);
  u += 0x7fff + ((u >> 16) & 1);  // RNE
  return (unsigned short)(u >> 16);
}
static __device__ __forceinline__ float bf2f(unsigned short u) {
  uint32_t x = (uint32_t)u << 16;
  return __builtin_bit_cast(float, x);
}
static __device__ __forceinline__ float bflo(uint32_t u) {
  return __builtin_bit_cast(float, u << 16);
}
static __device__ __forceinline__ float bfhi(uint32_t u) {
  return __builtin_bit_cast(float, u & 0xffff0000u);
}

// ---------------------------------------------------------------------------
// Depthwise 3x3 scalar (62x62 tensors), fp32 out, bias+residual.
// ---------------------------------------------------------------------------
__global__ void dwconv3_kernel(const float* __restrict__ x, const float* __restrict__ w,
                               const float* __restrict__ bias, float* __restrict__ y,
                               int C, int H, int W, int total, int residual) {
  int i = blockIdx.x * 256 + threadIdx.x;
  if (i >= total) return;
  int wx = i % W;
  int t = i / W;
  int hy = t % H;
  int bc = t / H;
  int c = bc % C;
  const float* xb = x + (size_t)bc * H * W;
  const float* wc = w + c * 9;
  float s = bias ? bias[c] : 0.0f;
  for (int di = -1; di <= 1; di++) {
    int h2 = hy + di;
    if (h2 < 0 || h2 >= H) continue;
    for (int dj = -1; dj <= 1; dj++) {
      int w2 = wx + dj;
      if (w2 < 0 || w2 >= W) continue;
      s += xb[(size_t)h2 * W + w2] * wc[(di + 1) * 3 + (dj + 1)];
    }
  }
  if (residual) s += xb[(size_t)hy * W + wx];
  y[i] = s;
}

// ---------------------------------------------------------------------------
// Depthwise 3x3 x-path: fp32 NCHW in -> bf16 NCHW out, residual. 4 px/thread.
// ---------------------------------------------------------------------------
__global__ void dwconv4_bf16_kernel(const float* __restrict__ x, const float* __restrict__ w,
                                    const float* __restrict__ bias,
                                    unsigned short* __restrict__ y, int total4) {
  int i = blockIdx.x * 256 + threadIdx.x;
  if (i >= total4) return;
  int W4 = HX >> 2;
  int wq = (i % W4) * 4;
  int t = i / W4;
  int hy = t % HX;
  int bc = t / HX;
  int c = bc & 127;
  const float* xb = x + (size_t)bc * HXW;
  const float* wc = w + c * 9;
  float bv = bias[c];
  float s0 = bv, s1 = bv, s2 = bv, s3 = bv;
  for (int di = -1; di <= 1; di++) {
    int h2 = hy + di;
    if (h2 < 0 || h2 >= HX) continue;
    const float* row = xb + (size_t)h2 * HX + wq;
    float4 cv = *(const float4*)row;
    float lf = (wq > 0) ? row[-1] : 0.0f;
    float rt = (wq + 4 < HX) ? row[4] : 0.0f;
    float w0 = wc[(di + 1) * 3 + 0];
    float w1 = wc[(di + 1) * 3 + 1];
    float w2 = wc[(di + 1) * 3 + 2];
    s0 += w0 * lf   + w1 * cv.x + w2 * cv.y;
    s1 += w0 * cv.x + w1 * cv.y + w2 * cv.z;
    s2 += w0 * cv.y + w1 * cv.z + w2 * cv.w;
    s3 += w0 * cv.z + w1 * cv.w + w2 * rt;
  }
  {
    float4 cc = *(const float4*)(xb + (size_t)hy * HX + wq);
    s0 += cc.x; s1 += cc.y; s2 += cc.z; s3 += cc.w;
  }
  uint2 d;
  d.x = (uint32_t)f2bf(s0) | ((uint32_t)f2bf(s1) << 16);
  d.y = (uint32_t)f2bf(s2) | ((uint32_t)f2bf(s3) << 16);
  *(uint2*)(y + (size_t)bc * HXW + (size_t)hy * HX + wq) = d;
}

// ---------------------------------------------------------------------------
// fp32 -> bf16 flat convert (for w_kv).
// ---------------------------------------------------------------------------
__global__ void cvt_bf16_kernel(const float* __restrict__ src, unsigned short* __restrict__ dst,
                                int n) {
  int i = blockIdx.x * 256 + threadIdx.x;
  if (i < n) dst[i] = f2bf(src[i]);
}

// ---------------------------------------------------------------------------
// Depthwise 3x3 q path: fp32 NCHW in -> bf16 NHWC out, pre-scaled by 32^-0.5.
// ---------------------------------------------------------------------------
__global__ void dwconv_q_kernel(const float* __restrict__ x, const float* __restrict__ w,
                                unsigned short* __restrict__ qn, int total) {
  int i = blockIdx.x * 256 + threadIdx.x;
  if (i >= total) return;
  int wx = i % HS;
  int t = i / HS;
  int hy = t % HS;
  int bc = t / HS;
  int c = bc & 127;
  int b = bc >> 7;
  const float* xb = x + (size_t)bc * HSW;
  const float* wc = w + c * 9;
  float s = 0.0f;
  for (int di = -1; di <= 1; di++) {
    int h2 = hy + di;
    if (h2 < 0 || h2 >= HS) continue;
    for (int dj = -1; dj <= 1; dj++) {
      int w2 = wx + dj;
      if (w2 < 0 || w2 >= HS) continue;
      s += xb[(size_t)h2 * HS + w2] * wc[(di + 1) * 3 + (dj + 1)];
    }
  }
  qn[((size_t)(b * HSW + hy * HS + wx)) * 128 + c] = f2bf(s * 0.17677669529663688f);
}

// ---------------------------------------------------------------------------
// MFMA 1x1 conv kv path. 17.4 KB LDS (X-stage and output-stage share one
// [px][128] stride-136 buffer; output flushed in two 128-o halves) ->
// ~6-8 blocks/CU. B-fragment loads software-pipelined with CLAMPED
// unconditional prefetch (no branch-around-load). Grid (961, 2).
// ---------------------------------------------------------------------------
__global__ __launch_bounds__(256) void conv1_kv_mfma_kernel(
    const unsigned short* __restrict__ xpb,  // (2,128,61504) bf16 NCHW
    const unsigned short* __restrict__ wkb,  // (256,128) bf16
    unsigned short* __restrict__ y) {        // (2,61504,256) bf16 NHWC
  int b = blockIdx.y;
  int p0 = blockIdx.x * 64;
  int tid = threadIdx.x;
  int wave = tid >> 6, lane = tid & 63, quad = lane >> 4, l15 = lane & 15;
  __shared__ __align__(16) unsigned short lds[64 * 136];  // 17,408 B

  // phase 1: stage X-tile as xs[px][c], stride 136
  {
    int c = tid >> 1, half = tid & 1;
    const unsigned short* src = xpb + ((size_t)(b * 128 + c)) * HXW + p0 + half * 32;
#pragma unroll
    for (int j = 0; j < 8; j++) {
      uint2 v = *(const uint2*)(src + j * 4);
      int px = half * 32 + j * 4;
      lds[(px + 0) * 136 + c] = (unsigned short)(v.x & 0xffff);
      lds[(px + 1) * 136 + c] = (unsigned short)(v.x >> 16);
      lds[(px + 2) * 136 + c] = (unsigned short)(v.y & 0xffff);
      lds[(px + 3) * 136 + c] = (unsigned short)(v.y >> 16);
    }
  }
  __syncthreads();
  bf16x8 A[4];
#pragma unroll
  for (int kb = 0; kb < 4; kb++)
    A[kb] = __builtin_bit_cast(bf16x8,
        *(const uint4*)&lds[(wave * 16 + l15) * 136 + kb * 32 + quad * 8]);
  __syncthreads();  // xs dead; lds becomes os[px][o-half] stride 136

  const f32x4 zf = {0.f, 0.f, 0.f, 0.f};
  const unsigned short* wrow = wkb + (size_t)l15 * 128 + quad * 8;
#define LOADB(OT, B0, B1, B2, B3)                                   \
  {                                                                 \
    const unsigned short* wb = wrow + (size_t)(OT) * 2048;          \
    B0 = *(const uint4*)(wb);                                       \
    B1 = *(const uint4*)(wb + 32);                                  \
    B2 = *(const uint4*)(wb + 64);                                  \
    B3 = *(const uint4*)(wb + 96);                                  \
  }

#pragma unroll 1
  for (int h = 0; h < 2; h++) {
    uint4 c0, c1, c2, c3, n0, n1, n2, n3;
    LOADB(h * 8, c0, c1, c2, c3)
#pragma unroll 1
    for (int ot = 0; ot < 8; ot++) {
      int otn = (ot < 7) ? (h * 8 + ot + 1) : (h * 8 + 7);  // clamped, branch-free
      LOADB(otn, n0, n1, n2, n3)
      f32x4 D = zf;
      D = __builtin_amdgcn_mfma_f32_16x16x32_bf16(A[0], __builtin_bit_cast(bf16x8, c0), D, 0, 0, 0);
      D = __builtin_amdgcn_mfma_f32_16x16x32_bf16(A[1], __builtin_bit_cast(bf16x8, c1), D, 0, 0, 0);
      D = __builtin_amdgcn_mfma_f32_16x16x32_bf16(A[2], __builtin_bit_cast(bf16x8, c2), D, 0, 0, 0);
      D = __builtin_amdgcn_mfma_f32_16x16x32_bf16(A[3], __builtin_bit_cast(bf16x8, c3), D, 0, 0, 0);
#pragma unroll
      for (int r = 0; r < 4; r++)
        lds[(wave * 16 + quad * 4 + r) * 136 + ot * 16 + l15] = f2bf(D[r]);
      c0 = n0; c1 = n1; c2 = n2; c3 = n3;
    }
    __syncthreads();
    {  // flush this o-half: 64 px x 128 o, 64 B per lane, coalesced
      int px = tid >> 2, og = (tid & 3) * 32;
      const uint4* srcp = (const uint4*)&lds[px * 136 + og];
      uint4* dstp = (uint4*)(y + ((size_t)b * HXW + p0 + px) * 256 + h * 128 + og);
#pragma unroll
      for (int j = 0; j < 4; j++) dstp[j] = srcp[j];
    }
    __syncthreads();
  }
#undef LOADB
}

// ---------------------------------------------------------------------------
// Fused depthwise 3x3 K/V from bf16 NHWC tkv, channel-quad lanes.
// Branch-free clamped tap loads (round-13 win). Grid (8, 124, 2).
// ---------------------------------------------------------------------------
struct Tap9 { uint2 u00, u01, u02, u10, u11, u12, u20, u21, u22; };

__global__ __launch_bounds__(256) void dwconv_kv_kernel(const unsigned short* __restrict__ tkv,
                                                        const float* __restrict__ w,
                                                        unsigned short* __restrict__ kT,
                                                        unsigned short* __restrict__ vv) {
  int strip = blockIdx.x;                      // 0..7
  int x0 = (strip == 7) ? 216 : strip * 32;
  int g = blockIdx.y;                          // 0..123
  int b = blockIdx.z;
  int tid = threadIdx.x;
  int cq = tid & 63;                           // channel quad (lane)
  int pg = tid >> 6;                           // 0..3 (wave-uniform)
  int ch0 = cq * 4;
  float wr[4][9];
#pragma unroll
  for (int j = 0; j < 4; j++)
#pragma unroll
    for (int t9 = 0; t9 < 9; t9++) wr[j][t9] = w[(ch0 + j) * 9 + t9];

  __shared__ unsigned short vt[128 * 35];      // [ch][px] stride 35 (9 KB)
  const unsigned short* base = tkv + (size_t)b * HXW * 256 + ch0;
  const uint2 z2 = {0u, 0u};

#pragma unroll 1
  for (int r = 0; r < 2; r++) {
    int hy = g * 2 + r;
    const unsigned short* r1 = base + (size_t)hy * HX * 256;
    const unsigned short* r0 = (hy > 0) ? (r1 - (size_t)HX * 256) : r1;       // clamped
    const unsigned short* r2 = (hy < HX - 1) ? (r1 + (size_t)HX * 256) : r1;  // clamped
    bool vtop = hy > 0, vbot = hy < HX - 1;

    auto load9 = [&](int px) {
      Tap9 t;
      int xc = x0 + px;
      size_t offC = (size_t)xc * 256;
      size_t offL = offC - ((xc > 0) ? 256 : 0);        // clamped
      size_t offR = offC + ((xc < HX - 1) ? 256 : 0);   // clamped
      t.u00 = *(const uint2*)(r0 + offL);
      t.u01 = *(const uint2*)(r0 + offC);
      t.u02 = *(const uint2*)(r0 + offR);
      t.u10 = *(const uint2*)(r1 + offL);
      t.u11 = *(const uint2*)(r1 + offC);
      t.u12 = *(const uint2*)(r1 + offR);
      t.u20 = *(const uint2*)(r2 + offL);
      t.u21 = *(const uint2*)(r2 + offC);
      t.u22 = *(const uint2*)(r2 + offR);
      return t;
    };
    auto maskcomp9 = [&](Tap9 t, int px) {
      int xc = x0 + px;
      if (!vtop) { t.u00 = z2; t.u01 = z2; t.u02 = z2; }
      if (!vbot) { t.u20 = z2; t.u21 = z2; t.u22 = z2; }
      if (xc == 0) { t.u00 = z2; t.u10 = z2; t.u20 = z2; }
      if (xc == HX - 1) { t.u02 = z2; t.u12 = z2; t.u22 = z2; }
      float o0 = 0.f, o1 = 0.f, o2 = 0.f, o3 = 0.f;
      o0 += wr[0][0] * bflo(t.u00.x); o1 += wr[1][0] * bfhi(t.u00.x);
      o2 += wr[2][0] * bflo(t.u00.y); o3 += wr[3][0] * bfhi(t.u00.y);
      o0 += wr[0][1] * bflo(t.u01.x); o1 += wr[1][1] * bfhi(t.u01.x);
      o2 += wr[2][1] * bflo(t.u01.y); o3 += wr[3][1] * bfhi(t.u01.y);
      o0 += wr[0][2] * bflo(t.u02.x); o1 += wr[1][2] * bfhi(t.u02.x);
      o2 += wr[2][2] * bflo(t.u02.y); o3 += wr[3][2] * bfhi(t.u02.y);
      o0 += wr[0][3] * bflo(t.u10.x); o1 += wr[1][3] * bfhi(t.u10.x);
      o2 += wr[2][3] * bflo(t.u10.y); o3 += wr[3][3] * bfhi(t.u10.y);
      o0 += wr[0][4] * bflo(t.u11.x); o1 += wr[1][4] * bfhi(t.u11.x);
      o2 += wr[2][4] * bflo(t.u11.y); o3 += wr[3][4] * bfhi(t.u11.y);
      o0 += wr[0][5] * bflo(t.u12.x); o1 += wr[1][5] * bfhi(t.u12.x);
      o2 += wr[2][5] * bflo(t.u12.y); o3 += wr[3][5] * bfhi(t.u12.y);
      o0 += wr[0][6] * bflo(t.u20.x); o1 += wr[1][6] * bfhi(t.u20.x);
      o2 += wr[2][6] * bflo(t.u20.y); o3 += wr[3][6] * bfhi(t.u20.y);
      o0 += wr[0][7] * bflo(t.u21.x); o1 += wr[1][7] * bfhi(t.u21.x);
      o2 += wr[2][7] * bflo(t.u21.y); o3 += wr[3][7] * bfhi(t.u21.y);
      o0 += wr[0][8] * bflo(t.u22.x); o1 += wr[1][8] * bfhi(t.u22.x);
      o2 += wr[2][8] * bflo(t.u22.y); o3 += wr[3][8] * bfhi(t.u22.y);
      if (cq < 32) {
        uint2 d;
        d.x = (uint32_t)f2bf(o0) | ((uint32_t)f2bf(o1) << 16);
        d.y = (uint32_t)f2bf(o2) | ((uint32_t)f2bf(o3) << 16);
        *(uint2*)(kT + ((size_t)b * HXW + (size_t)hy * HX + xc) * 128 + ch0) = d;
      } else {
        int c0 = ch0 - 128;
        vt[(c0 + 0) * 35 + px] = f2bf(o0);
        vt[(c0 + 1) * 35 + px] = f2bf(o1);
        vt[(c0 + 2) * 35 + px] = f2bf(o2);
        vt[(c0 + 3) * 35 + px] = f2bf(o3);
      }
    };

#pragma unroll 1
    for (int i = 0; i < 8; i += 2) {
      int pxA = pg + i * 4;
      int pxB = pg + (i + 1) * 4;
      Tap9 ta = load9(pxA);
      Tap9 tb = load9(pxB);
      maskcomp9(ta, pxA);
      maskcomp9(tb, pxB);
    }
    __syncthreads();
    {  // cooperative NCHW store of the V row
      int cv = tid & 127;
      int phx = (tid >> 7) * 16;
      unsigned short* dst = vv + ((size_t)(b * 128 + cv)) * HXW + (size_t)hy * HX + x0 + phx;
      const unsigned short* srcv = vt + cv * 35 + phx;
#pragma unroll
      for (int jj = 0; jj < 4; jj++) {
        uint2 d;
        d.x = (uint32_t)srcv[jj * 4 + 0] | ((uint32_t)srcv[jj * 4 + 1] << 16);
        d.y = (uint32_t)srcv[jj * 4 + 2] | ((uint32_t)srcv[jj * 4 + 3] << 16);
        *(uint2*)(dst + jj * 4) = d;
      }
    }
    __syncthreads();
  }
}

// ---------------------------------------------------------------------------
// 1x1 conv tiled SGEMM (fp32) — small tensors (q path, output projection).
// ---------------------------------------------------------------------------
template <int O>
__global__ __launch_bounds__(256) void conv1_kernel(const float* __restrict__ x,
                                                    const float* __restrict__ w,
                                                    float* __restrict__ y, int HW) {
  constexpr int K = 128;
  constexpr int BK = 32;
  __shared__ __align__(16) float ws_s[BK][64];
  __shared__ __align__(16) float xs_s[BK][64];
  int b = blockIdx.z;
  int o0 = blockIdx.y * 64;
  int p0 = blockIdx.x * 64;
  const float* xb = x + (size_t)b * K * HW;
  int tx = threadIdx.x & 15;
  int ty = threadIdx.x >> 4;
  float acc[4][4] = {};
  int lo = threadIdx.x >> 2;
  int lk = (threadIdx.x & 3) * 8;
  int lc = threadIdx.x >> 3;
  int lp = (threadIdx.x & 7) * 8;

  for (int k0 = 0; k0 < K; k0 += BK) {
    __syncthreads();
    {
      const float* wp = w + (size_t)(o0 + lo) * K + k0 + lk;
      float4 a = *(const float4*)wp;
      float4 bq = *(const float4*)(wp + 4);
      ws_s[lk + 0][lo] = a.x;  ws_s[lk + 1][lo] = a.y;
      ws_s[lk + 2][lo] = a.z;  ws_s[lk + 3][lo] = a.w;
      ws_s[lk + 4][lo] = bq.x; ws_s[lk + 5][lo] = bq.y;
      ws_s[lk + 6][lo] = bq.z; ws_s[lk + 7][lo] = bq.w;
    }
    {
      int p = p0 + lp;
      const float* xp = xb + (size_t)(k0 + lc) * HW;
      float4 a, bq;
      if (p + 7 < HW) {
        a = *(const float4*)(xp + p);
        bq = *(const float4*)(xp + p + 4);
      } else {
        float tv[8];
#pragma unroll
        for (int j = 0; j < 8; j++) tv[j] = (p + j < HW) ? xp[p + j] : 0.0f;
        a = make_float4(tv[0], tv[1], tv[2], tv[3]);
        bq = make_float4(tv[4], tv[5], tv[6], tv[7]);
      }
      *(float4*)&xs_s[lc][lp] = a;
      *(float4*)&xs_s[lc][lp + 4] = bq;
    }
    __syncthreads();
#pragma unroll
    for (int k = 0; k < BK; k++) {
      float4 wv = *(const float4*)&ws_s[k][ty * 4];
      float4 xv = *(const float4*)&xs_s[k][tx * 4];
      acc[0][0] += wv.x * xv.x; acc[0][1] += wv.x * xv.y; acc[0][2] += wv.x * xv.z; acc[0][3] += wv.x * xv.w;
      acc[1][0] += wv.y * xv.x; acc[1][1] += wv.y * xv.y; acc[1][2] += wv.y * xv.z; acc[1][3] += wv.y * xv.w;
      acc[2][0] += wv.z * xv.x; acc[2][1] += wv.z * xv.y; acc[2][2] += wv.z * xv.z; acc[2][3] += wv.z * xv.w;
      acc[3][0] += wv.w * xv.x; acc[3][1] += wv.w * xv.y; acc[3][2] += wv.w * xv.z; acc[3][3] += wv.w * xv.w;
    }
  }
  int p = p0 + tx * 4;
  float* yb = y + (size_t)b * O * HW + (size_t)(o0 + ty * 4) * HW;
#pragma unroll
  for (int j = 0; j < 4; j++) {
    float* yr = yb + (size_t)j * HW + p;
    if (p + 3 < HW) {
      *(float4*)yr = make_float4(acc[j][0], acc[j][1], acc[j][2], acc[j][3]);
    } else {
#pragma unroll
      for (int e = 0; e < 4; e++) if (p + e < HW) yr[e] = acc[j][e];
    }
  }
}

// ---------------------------------------------------------------------------
// MFMA windowed attention, head-pair blocks. 512 thr = 8 waves.
// Prefetch now branch-free (clamped row index, unconditional LOADROW).
// ---------------------------------------------------------------------------
__global__ __launch_bounds__(512) void attn_mfma_kernel(
    const unsigned short* __restrict__ qn,   // (2,62,62,128) bf16, pre-scaled
    const unsigned short* __restrict__ kT,   // (2,248,248,128) bf16 NHWC
    const unsigned short* __restrict__ vp,   // (2,128,248,248) bf16 NCHW
    float* __restrict__ o) {
  int n = blockIdx.x, hp = blockIdx.y, b = blockIdx.z;
  int wi = n / 10, wj = n % 10;
  int wave = threadIdx.x >> 6;
  int hd = wave & 1, oct = wave >> 1;
  int h = hp * 2 + hd;
  int lane = threadIdx.x & 63;
  int quad = lane >> 4;
  int l15 = lane & 15;
  int y0 = 24 * wi, x0 = 24 * wj;

  __shared__ __align__(16) unsigned short lds[20480];  // 40,960 B
  unsigned short* Pw = lds + wave * 2560;              // [q][40keys] 5KB/wave

  bf16x8 QB[4];
#pragma unroll
  for (int nt = 0; nt < 4; nt++) {
    int qq = nt * 16 + l15;
    int qy = 6 * wi + (qq >> 3), qx = 6 * wj + (qq & 7);
    QB[nt] = __builtin_bit_cast(bf16x8,
        *(const uint4*)(qn + ((size_t)(b * HSW + qy * HS + qx)) * 128 + h * 32 + quad * 8));
  }

  f32x4 Oacc[2][4];
#pragma unroll
  for (int a = 0; a < 2; a++)
#pragma unroll
    for (int c = 0; c < 4; c++) Oacc[a][c] = f32x4{0.f, 0.f, 0.f, 0.f};
  float lsum[4] = {0.f, 0.f, 0.f, 0.f};

  const unsigned short* kb = kT + (size_t)b * HXW * 128 + h * 32;
  const unsigned short* vb = vp + ((size_t)(b * 128 + h * 32)) * HXW;
  const f32x4 zf = {0.f, 0.f, 0.f, 0.f};

#define LOADROW(r, K0, K1, V0, V1)                                              \
  {                                                                             \
    int y = y0 + (r);                                                           \
    const unsigned short* krow = kb + ((size_t)(y * HX + x0)) * 128;            \
    K0 = *(const uint4*)(krow + (size_t)l15 * 128 + quad * 8);                  \
    K1 = *(const uint4*)(krow + (size_t)(16 + l15) * 128 + quad * 8);           \
    const unsigned short* vrow = vb + (size_t)y * HX + x0 + quad * 8;           \
    V0 = *(const uint4*)(vrow + (size_t)l15 * HXW);                             \
    V1 = *(const uint4*)(vrow + (size_t)(16 + l15) * HXW);                      \
  }

  auto compute = [&](uint4 k0, uint4 k1, uint4 v0, uint4 v1) {
    bf16x8 KA0 = __builtin_bit_cast(bf16x8, k0);
    bf16x8 KA1 = __builtin_bit_cast(bf16x8, k1);
    bf16x8 VA0 = __builtin_bit_cast(bf16x8, v0);
    bf16x8 VA1 = __builtin_bit_cast(bf16x8, v1);
    f32x4 S[2][4];
#pragma unroll
    for (int nt = 0; nt < 4; nt++) {
      S[0][nt] = __builtin_amdgcn_mfma_f32_16x16x32_bf16(KA0, QB[nt], zf, 0, 0, 0);
      S[1][nt] = __builtin_amdgcn_mfma_f32_16x16x32_bf16(KA1, QB[nt], zf, 0, 0, 0);
    }
#pragma unroll
    for (int nt = 0; nt < 4; nt++) {
      float pv[2][4];
      float cs = 0.f;
#pragma unroll
      for (int mt = 0; mt < 2; mt++)
#pragma unroll
        for (int r = 0; r < 4; r++) {
          pv[mt][r] = __expf(S[mt][nt][r]);
          cs += pv[mt][r];
        }
      lsum[nt] += cs;
#pragma unroll
      for (int mt = 0; mt < 2; mt++) {
        uint2 d;
        d.x = (uint32_t)f2bf(pv[mt][0]) | ((uint32_t)f2bf(pv[mt][1]) << 16);
        d.y = (uint32_t)f2bf(pv[mt][2]) | ((uint32_t)f2bf(pv[mt][3]) << 16);
        *(uint2*)(Pw + (16 * nt + l15) * 40 + 16 * mt + quad * 4) = d;
      }
    }
#pragma unroll
    for (int nt = 0; nt < 4; nt++) {
      bf16x8 PB = __builtin_bit_cast(bf16x8, *(const uint4*)(Pw + (16 * nt + l15) * 40 + quad * 8));
      Oacc[0][nt] = __builtin_amdgcn_mfma_f32_16x16x32_bf16(VA0, PB, Oacc[0][nt], 0, 0, 0);
      Oacc[1][nt] = __builtin_amdgcn_mfma_f32_16x16x32_bf16(VA1, PB, Oacc[1][nt], 0, 0, 0);
    }
  };

  int rbase = oct * 8;
  uint4 kA0, kA1, vA0, vA1, kB0, kB1, vB0, vB1;
  LOADROW(rbase + 0, kA0, kA1, vA0, vA1);
  LOADROW(rbase + 1, kB0, kB1, vB0, vB1);
#pragma unroll 1
  for (int r = 0; r < 8; r += 2) {
    compute(kA0, kA1, vA0, vA1);
    {
      int rn = (r + 2 < 8) ? (r + 2) : 6;  // clamped, branch-free
      LOADROW(rbase + rn, kA0, kA1, vA0, vA1);
    }
    compute(kB0, kB1, vB0, vB1);
    {
      int rn = (r + 3 < 8) ? (r + 3) : 7;  // clamped, branch-free
      LOADROW(rbase + rn, kB0, kB1, vB0, vB1);
    }
  }
#undef LOADROW

#pragma unroll
  for (int nt = 0; nt < 4; nt++) {
    lsum[nt] += __shfl_xor(lsum[nt], 16, 64);
    lsum[nt] += __shfl_xor(lsum[nt], 32, 64);
  }

  float* mO = (float*)lds;                 // [oct][32ch][64q]  32 KB
  float* mL = (float*)(lds + 16384);       // [oct][64q]
#pragma unroll 1
  for (int p = 0; p < 2; p++) {
    __syncthreads();
    if (hd == p) {
#pragma unroll
      for (int mt = 0; mt < 2; mt++)
#pragma unroll
        for (int nt = 0; nt < 4; nt++)
#pragma unroll
          for (int r = 0; r < 4; r++)
            mO[oct * 2048 + (16 * mt + quad * 4 + r) * 64 + 16 * nt + l15] = Oacc[mt][nt][r];
      if (quad == 0) {
#pragma unroll
        for (int nt = 0; nt < 4; nt++) mL[oct * 64 + nt * 16 + l15] = lsum[nt];
      }
    }
    __syncthreads();
    {
      int q = threadIdx.x & 63;
      int cg = threadIdx.x >> 6;  // 0..7 -> 4 ch each
      float inv = 1.0f / (mL[q] + mL[64 + q] + mL[128 + q] + mL[192 + q]);
      float* ob = o + (((size_t)(b * 100 + n)) * 128 + (hp * 2 + p) * 32 + cg * 4) * 64 + q;
#pragma unroll
      for (int e = 0; e < 4; e++) {
        int ch = cg * 4 + e;
        float s = mO[ch * 64 + q] + mO[2048 + ch * 64 + q] +
                  mO[4096 + ch * 64 + q] + mO[6144 + ch * 64 + q];
        ob[(size_t)e * 64] = s * inv;
      }
    }
  }
}

// ---------------------------------------------------------------------------
// Reverse: scatter-average overlapping 8x8 windows (step 6) into (2,128,62,62)
// ---------------------------------------------------------------------------
__global__ void reverse_kernel(const float* __restrict__ win, float* __restrict__ out) {
  int i = blockIdx.x * 256 + threadIdx.x;
  const int total = 2 * 128 * HSW;
  if (i >= total) return;
  int x = i % HS;
  int t = i / HS;
  int y = t % HS;
  t /= HS;
  int c = t % 128;
  int b = t / 128;
  int wi0 = (y >= 7) ? (y - 2) / 6 : 0;
  int wi1 = min(9, y / 6);
  int wj0 = (x >= 7) ? (x - 2) / 6 : 0;
  int wj1 = min(9, x / 6);
  float s = 0.0f;
  for (int wi = wi0; wi <= wi1; wi++)
    for (int wj = wj0; wj <= wj1; wj++) {
      int di = y - 6 * wi, dj = x - 6 * wj;
      s += win[(((size_t)(b * 100 + wi * 10 + wj)) * 128 + c) * 64 + di * 8 + dj];
    }
  float cnt = (float)((wi1 - wi0 + 1) * (wj1 - wj0 + 1));
  out[i] = s / cnt;
}

// ---------------------------------------------------------------------------
extern "C" void kernel_launch(void* const* d_in, const int* in_sizes, int n_in,
                              void* d_out, int out_size, void* d_ws, size_t ws_size,
                              hipStream_t stream) {
  const float* x      = (const float*)d_in[0];
  const float* sp     = (const float*)d_in[1];
  const float* w_pos  = (const float*)d_in[2];
  const float* b_pos  = (const float*)d_in[3];
  const float* w_q    = (const float*)d_in[4];
  const float* w_qdw  = (const float*)d_in[5];
  const float* w_kv   = (const float*)d_in[6];
  const float* w_kvdw = (const float*)d_in[7];
  const float* w_out  = (const float*)d_in[8];
  float* out = (float*)d_out;

  const size_t N_x   = (size_t)2 * 128 * HXW;  // 15,745,024
  const size_t N_t   = (size_t)2 * 256 * HXW;
  const size_t N_s   = (size_t)2 * 128 * HSW;
  const size_t N_att = (size_t)2 * 100 * 128 * 64;

  float* ws = (float*)d_ws;
  unsigned short* xpb = (unsigned short*)ws;
  unsigned short* kT  = (unsigned short*)ws;
  unsigned short* vv  = kT + N_x;
  unsigned short* tkv = (unsigned short*)(ws + N_x);
  float* att = ws + N_x;
  float* rev = att + N_att;
  float* spp = ws + N_x + N_t / 2;
  float* tq  = spp + N_s;
  unsigned short* qn  = (unsigned short*)(tq + N_s);
  unsigned short* wkb = qn + N_s;              // 32768 ushorts
  (void)ws_size; (void)in_sizes; (void)n_in; (void)out_size;

  // 0. wkb = bf16(w_kv)
  cvt_bf16_kernel<<<128, 256, 0, stream>>>(w_kv, wkb, 256 * 128);
  // 1. xpb = bf16(x + dwconv3(x, w_pos, b_pos))   (bf16 NCHW)
  {
    int total4 = (int)(N_x / 4);
    dwconv4_bf16_kernel<<<(total4 + 255) / 256, 256, 0, stream>>>(x, w_pos, b_pos, xpb, total4);
  }
  // 2. spp = sp + dwconv3(sp, w_pos, b_pos)
  {
    int total = (int)N_s;
    dwconv3_kernel<<<(total + 255) / 256, 256, 0, stream>>>(sp, w_pos, b_pos, spp, 128, HS, HS, total, 1);
  }
  // 3. tq = conv1(spp, w_q)
  {
    int HW = HSW;
    dim3 grid((HW + 63) / 64, 2, 2);
    conv1_kernel<128><<<grid, 256, 0, stream>>>(spp, w_q, tq, HW);
  }
  // 4. qn = bf16_nhwc(dwconv3(tq, w_qdw)) * 32^-0.5
  {
    int total = (int)N_s;
    dwconv_q_kernel<<<(total + 255) / 256, 256, 0, stream>>>(tq, w_qdw, qn, total);
  }
  // 5. tkv = bf16_nhwc(mfma_conv1(xpb, wkb))   (xpb dead after)
  {
    dim3 grid(HXW / 64, 2);
    conv1_kv_mfma_kernel<<<grid, 256, 0, stream>>>(xpb, wkb, tkv);
  }
  // 6. kT (NHWC) + vv (NCHW) = bf16(dwconv3(tkv, w_kvdw))   (overwrites xpb)
  {
    dim3 grid(8, 124, 2);
    dwconv_kv_kernel<<<grid, 256, 0, stream>>>(tkv, w_kvdw, kT, vv);
  }
  // 7. attention -> att (2,100,128,64)
  {
    dim3 grid(100, 2, 2);
    attn_mfma_kernel<<<grid, 512, 0, stream>>>(qn, kT, vv, att);
  }
  // 8. rev = reverse(att)
  {
    int total = (int)N_s;
    reverse_kernel<<<(total + 255) / 256, 256, 0, stream>>>(att, rev);
  }
  // 9. out = conv1(rev, w_out)
  {
    int HW = HSW;
    dim3 grid((HW + 63) / 64, 2, 2);
    conv1_kernel<128><<<grid, 256, 0, stream>>>(rev, w_out, out, HW);
  }
}

// Round 15
// 316.749 us; speedup vs baseline: 1.1417x; 1.1417x over previous
//
#include <hip/hip_runtime.h>
#include <cstdint>

#define HS 62
#define HX 248
#define HXW (HX * HX)  // 61504
#define HSW (HS * HS)  // 3844

typedef __attribute__((ext_vector_type(8))) short bf16x8;
typedef __attribute__((ext_vector_type(4))) float f32x4;

static __device__ __forceinline__ unsigned short f2bf(float f) {
  uint32_t u = __builtin_bit_cast(uint32_t, f);
  u += 0x7fff + ((u >> 16) & 1);  // RNE
  return (unsigned short)(u >> 16);
}
static __device__ __forceinline__ float bf2f(unsigned short u) {
  uint32_t x = (uint32_t)u << 16;
  return __builtin_bit_cast(float, x);
}
static __device__ __forceinline__ float bflo(uint32_t u) {
  return __builtin_bit_cast(float, u << 16);
}
static __device__ __forceinline__ float bfhi(uint32_t u) {
  return __builtin_bit_cast(float, u & 0xffff0000u);
}

// ---------------------------------------------------------------------------
// Depthwise 3x3 scalar (62x62 tensors), fp32 out, bias+residual.
// ---------------------------------------------------------------------------
__global__ void dwconv3_kernel(const float* __restrict__ x, const float* __restrict__ w,
                               const float* __restrict__ bias, float* __restrict__ y,
                               int C, int H, int W, int total, int residual) {
  int i = blockIdx.x * 256 + threadIdx.x;
  if (i >= total) return;
  int wx = i % W;
  int t = i / W;
  int hy = t % H;
  int bc = t / H;
  int c = bc % C;
  const float* xb = x + (size_t)bc * H * W;
  const float* wc = w + c * 9;
  float s = bias ? bias[c] : 0.0f;
  for (int di = -1; di <= 1; di++) {
    int h2 = hy + di;
    if (h2 < 0 || h2 >= H) continue;
    for (int dj = -1; dj <= 1; dj++) {
      int w2 = wx + dj;
      if (w2 < 0 || w2 >= W) continue;
      s += xb[(size_t)h2 * W + w2] * wc[(di + 1) * 3 + (dj + 1)];
    }
  }
  if (residual) s += xb[(size_t)hy * W + wx];
  y[i] = s;
}

// ---------------------------------------------------------------------------
// Depthwise 3x3 x-path: fp32 NCHW in -> bf16 NCHW out, residual. 4 px/thread.
// ---------------------------------------------------------------------------
__global__ void dwconv4_bf16_kernel(const float* __restrict__ x, const float* __restrict__ w,
                                    const float* __restrict__ bias,
                                    unsigned short* __restrict__ y, int total4) {
  int i = blockIdx.x * 256 + threadIdx.x;
  if (i >= total4) return;
  int W4 = HX >> 2;
  int wq = (i % W4) * 4;
  int t = i / W4;
  int hy = t % HX;
  int bc = t / HX;
  int c = bc & 127;
  const float* xb = x + (size_t)bc * HXW;
  const float* wc = w + c * 9;
  float bv = bias[c];
  float s0 = bv, s1 = bv, s2 = bv, s3 = bv;
  for (int di = -1; di <= 1; di++) {
    int h2 = hy + di;
    if (h2 < 0 || h2 >= HX) continue;
    const float* row = xb + (size_t)h2 * HX + wq;
    float4 cv = *(const float4*)row;
    float lf = (wq > 0) ? row[-1] : 0.0f;
    float rt = (wq + 4 < HX) ? row[4] : 0.0f;
    float w0 = wc[(di + 1) * 3 + 0];
    float w1 = wc[(di + 1) * 3 + 1];
    float w2 = wc[(di + 1) * 3 + 2];
    s0 += w0 * lf   + w1 * cv.x + w2 * cv.y;
    s1 += w0 * cv.x + w1 * cv.y + w2 * cv.z;
    s2 += w0 * cv.y + w1 * cv.z + w2 * cv.w;
    s3 += w0 * cv.z + w1 * cv.w + w2 * rt;
  }
  {
    float4 cc = *(const float4*)(xb + (size_t)hy * HX + wq);
    s0 += cc.x; s1 += cc.y; s2 += cc.z; s3 += cc.w;
  }
  uint2 d;
  d.x = (uint32_t)f2bf(s0) | ((uint32_t)f2bf(s1) << 16);
  d.y = (uint32_t)f2bf(s2) | ((uint32_t)f2bf(s3) << 16);
  *(uint2*)(y + (size_t)bc * HXW + (size_t)hy * HX + wq) = d;
}

// ---------------------------------------------------------------------------
// fp32 -> bf16 flat convert (for w_kv).
// ---------------------------------------------------------------------------
__global__ void cvt_bf16_kernel(const float* __restrict__ src, unsigned short* __restrict__ dst,
                                int n) {
  int i = blockIdx.x * 256 + threadIdx.x;
  if (i < n) dst[i] = f2bf(src[i]);
}

// ---------------------------------------------------------------------------
// Depthwise 3x3 q path: fp32 NCHW in -> bf16 NHWC out, pre-scaled by 32^-0.5.
// ---------------------------------------------------------------------------
__global__ void dwconv_q_kernel(const float* __restrict__ x, const float* __restrict__ w,
                                unsigned short* __restrict__ qn, int total) {
  int i = blockIdx.x * 256 + threadIdx.x;
  if (i >= total) return;
  int wx = i % HS;
  int t = i / HS;
  int hy = t % HS;
  int bc = t / HS;
  int c = bc & 127;
  int b = bc >> 7;
  const float* xb = x + (size_t)bc * HSW;
  const float* wc = w + c * 9;
  float s = 0.0f;
  for (int di = -1; di <= 1; di++) {
    int h2 = hy + di;
    if (h2 < 0 || h2 >= HS) continue;
    for (int dj = -1; dj <= 1; dj++) {
      int w2 = wx + dj;
      if (w2 < 0 || w2 >= HS) continue;
      s += xb[(size_t)h2 * HS + w2] * wc[(di + 1) * 3 + (dj + 1)];
    }
  }
  qn[((size_t)(b * HSW + hy * HS + wx)) * 128 + c] = f2bf(s * 0.17677669529663688f);
}

// ---------------------------------------------------------------------------
// MFMA 1x1 conv kv path, v3: weights staged in LDS per 64-o quarter.
// (Rounds 9-14 floor: B-fragments read from global hit the same 32 KB wkb
//  region with 16 B used per 128 B L2 line -> ~3 GB of L2 line-requests,
//  L2-request-rate bound. LDS staging cuts that to 123 MB coalesced.)
// Block = 64 px x 256 o, 4 waves. bufA: X stage [px][c] s136 -> output
// stage [px][o-half] s136. bufW: weight quarter [o][c] s136. 34.8 KB LDS.
// Grid (961, 2).
// ---------------------------------------------------------------------------
__global__ __launch_bounds__(256) void conv1_kv_mfma_kernel(
    const unsigned short* __restrict__ xpb,  // (2,128,61504) bf16 NCHW
    const unsigned short* __restrict__ wkb,  // (256,128) bf16
    unsigned short* __restrict__ y) {        // (2,61504,256) bf16 NHWC
  int b = blockIdx.y;
  int p0 = blockIdx.x * 64;
  int tid = threadIdx.x;
  int wave = tid >> 6, lane = tid & 63, quad = lane >> 4, l15 = lane & 15;
  __shared__ __align__(16) unsigned short bufA[64 * 136];  // 17,408 B
  __shared__ __align__(16) unsigned short bufW[64 * 136];  // 17,408 B

  // phase 1: stage X-tile as bufA[px][c], stride 136
  {
    int c = tid >> 1, half = tid & 1;
    const unsigned short* src = xpb + ((size_t)(b * 128 + c)) * HXW + p0 + half * 32;
#pragma unroll
    for (int j = 0; j < 8; j++) {
      uint2 v = *(const uint2*)(src + j * 4);
      int px = half * 32 + j * 4;
      bufA[(px + 0) * 136 + c] = (unsigned short)(v.x & 0xffff);
      bufA[(px + 1) * 136 + c] = (unsigned short)(v.x >> 16);
      bufA[(px + 2) * 136 + c] = (unsigned short)(v.y & 0xffff);
      bufA[(px + 3) * 136 + c] = (unsigned short)(v.y >> 16);
    }
  }
  __syncthreads();
  bf16x8 A[4];
#pragma unroll
  for (int kb = 0; kb < 4; kb++)
    A[kb] = __builtin_bit_cast(bf16x8,
        *(const uint4*)&bufA[(wave * 16 + l15) * 136 + kb * 32 + quad * 8]);
  // bufA becomes the output stage after the next barrier.

  const f32x4 zf = {0.f, 0.f, 0.f, 0.f};
#pragma unroll 1
  for (int h = 0; h < 2; h++) {
#pragma unroll 1
    for (int oq = 0; oq < 2; oq++) {
      __syncthreads();  // bufW reusable; (h>0: bufA flush complete)
      {  // cooperative coalesced load of one 64-o weight quarter -> bufW
        int orow = tid >> 2;          // 0..63
        int cseg = (tid & 3) * 32;    // 0,32,64,96
        const unsigned short* src = wkb + (size_t)(h * 128 + oq * 64 + orow) * 128 + cseg;
        unsigned short* dst = &bufW[orow * 136 + cseg];
        *(uint4*)(dst)      = *(const uint4*)(src);
        *(uint4*)(dst + 8)  = *(const uint4*)(src + 8);
        *(uint4*)(dst + 16) = *(const uint4*)(src + 16);
        *(uint4*)(dst + 24) = *(const uint4*)(src + 24);
      }
      __syncthreads();
#pragma unroll
      for (int ot = 0; ot < 4; ot++) {
        const unsigned short* wrow = &bufW[(ot * 16 + l15) * 136 + quad * 8];
        f32x4 D = zf;
        D = __builtin_amdgcn_mfma_f32_16x16x32_bf16(A[0], __builtin_bit_cast(bf16x8, *(const uint4*)(wrow)),      D, 0, 0, 0);
        D = __builtin_amdgcn_mfma_f32_16x16x32_bf16(A[1], __builtin_bit_cast(bf16x8, *(const uint4*)(wrow + 32)), D, 0, 0, 0);
        D = __builtin_amdgcn_mfma_f32_16x16x32_bf16(A[2], __builtin_bit_cast(bf16x8, *(const uint4*)(wrow + 64)), D, 0, 0, 0);
        D = __builtin_amdgcn_mfma_f32_16x16x32_bf16(A[3], __builtin_bit_cast(bf16x8, *(const uint4*)(wrow + 96)), D, 0, 0, 0);
#pragma unroll
        for (int r = 0; r < 4; r++)
          bufA[(wave * 16 + quad * 4 + r) * 136 + (oq * 4 + ot) * 16 + l15] = f2bf(D[r]);
      }
    }
    __syncthreads();
    {  // flush this o-half: 64 px x 128 o, coalesced
      int px = tid >> 2, og = (tid & 3) * 32;
      const uint4* srcp = (const uint4*)&bufA[px * 136 + og];
      uint4* dstp = (uint4*)(y + ((size_t)b * HXW + p0 + px) * 256 + h * 128 + og);
#pragma unroll
      for (int j = 0; j < 4; j++) dstp[j] = srcp[j];
    }
  }
}

// ---------------------------------------------------------------------------
// Fused depthwise 3x3 K/V from bf16 NHWC tkv, channel-quad lanes.
// Branch-free clamped tap loads (round-13 win). Grid (8, 124, 2).
// ---------------------------------------------------------------------------
struct Tap9 { uint2 u00, u01, u02, u10, u11, u12, u20, u21, u22; };

__global__ __launch_bounds__(256) void dwconv_kv_kernel(const unsigned short* __restrict__ tkv,
                                                        const float* __restrict__ w,
                                                        unsigned short* __restrict__ kT,
                                                        unsigned short* __restrict__ vv) {
  int strip = blockIdx.x;                      // 0..7
  int x0 = (strip == 7) ? 216 : strip * 32;
  int g = blockIdx.y;                          // 0..123
  int b = blockIdx.z;
  int tid = threadIdx.x;
  int cq = tid & 63;                           // channel quad (lane)
  int pg = tid >> 6;                           // 0..3 (wave-uniform)
  int ch0 = cq * 4;
  float wr[4][9];
#pragma unroll
  for (int j = 0; j < 4; j++)
#pragma unroll
    for (int t9 = 0; t9 < 9; t9++) wr[j][t9] = w[(ch0 + j) * 9 + t9];

  __shared__ unsigned short vt[128 * 35];      // [ch][px] stride 35 (9 KB)
  const unsigned short* base = tkv + (size_t)b * HXW * 256 + ch0;
  const uint2 z2 = {0u, 0u};

#pragma unroll 1
  for (int r = 0; r < 2; r++) {
    int hy = g * 2 + r;
    const unsigned short* r1 = base + (size_t)hy * HX * 256;
    const unsigned short* r0 = (hy > 0) ? (r1 - (size_t)HX * 256) : r1;       // clamped
    const unsigned short* r2 = (hy < HX - 1) ? (r1 + (size_t)HX * 256) : r1;  // clamped
    bool vtop = hy > 0, vbot = hy < HX - 1;

    auto load9 = [&](int px) {
      Tap9 t;
      int xc = x0 + px;
      size_t offC = (size_t)xc * 256;
      size_t offL = offC - ((xc > 0) ? 256 : 0);        // clamped
      size_t offR = offC + ((xc < HX - 1) ? 256 : 0);   // clamped
      t.u00 = *(const uint2*)(r0 + offL);
      t.u01 = *(const uint2*)(r0 + offC);
      t.u02 = *(const uint2*)(r0 + offR);
      t.u10 = *(const uint2*)(r1 + offL);
      t.u11 = *(const uint2*)(r1 + offC);
      t.u12 = *(const uint2*)(r1 + offR);
      t.u20 = *(const uint2*)(r2 + offL);
      t.u21 = *(const uint2*)(r2 + offC);
      t.u22 = *(const uint2*)(r2 + offR);
      return t;
    };
    auto maskcomp9 = [&](Tap9 t, int px) {
      int xc = x0 + px;
      if (!vtop) { t.u00 = z2; t.u01 = z2; t.u02 = z2; }
      if (!vbot) { t.u20 = z2; t.u21 = z2; t.u22 = z2; }
      if (xc == 0) { t.u00 = z2; t.u10 = z2; t.u20 = z2; }
      if (xc == HX - 1) { t.u02 = z2; t.u12 = z2; t.u22 = z2; }
      float o0 = 0.f, o1 = 0.f, o2 = 0.f, o3 = 0.f;
      o0 += wr[0][0] * bflo(t.u00.x); o1 += wr[1][0] * bfhi(t.u00.x);
      o2 += wr[2][0] * bflo(t.u00.y); o3 += wr[3][0] * bfhi(t.u00.y);
      o0 += wr[0][1] * bflo(t.u01.x); o1 += wr[1][1] * bfhi(t.u01.x);
      o2 += wr[2][1] * bflo(t.u01.y); o3 += wr[3][1] * bfhi(t.u01.y);
      o0 += wr[0][2] * bflo(t.u02.x); o1 += wr[1][2] * bfhi(t.u02.x);
      o2 += wr[2][2] * bflo(t.u02.y); o3 += wr[3][2] * bfhi(t.u02.y);
      o0 += wr[0][3] * bflo(t.u10.x); o1 += wr[1][3] * bfhi(t.u10.x);
      o2 += wr[2][3] * bflo(t.u10.y); o3 += wr[3][3] * bfhi(t.u10.y);
      o0 += wr[0][4] * bflo(t.u11.x); o1 += wr[1][4] * bfhi(t.u11.x);
      o2 += wr[2][4] * bflo(t.u11.y); o3 += wr[3][4] * bfhi(t.u11.y);
      o0 += wr[0][5] * bflo(t.u12.x); o1 += wr[1][5] * bfhi(t.u12.x);
      o2 += wr[2][5] * bflo(t.u12.y); o3 += wr[3][5] * bfhi(t.u12.y);
      o0 += wr[0][6] * bflo(t.u20.x); o1 += wr[1][6] * bfhi(t.u20.x);
      o2 += wr[2][6] * bflo(t.u20.y); o3 += wr[3][6] * bfhi(t.u20.y);
      o0 += wr[0][7] * bflo(t.u21.x); o1 += wr[1][7] * bfhi(t.u21.x);
      o2 += wr[2][7] * bflo(t.u21.y); o3 += wr[3][7] * bfhi(t.u21.y);
      o0 += wr[0][8] * bflo(t.u22.x); o1 += wr[1][8] * bfhi(t.u22.x);
      o2 += wr[2][8] * bflo(t.u22.y); o3 += wr[3][8] * bfhi(t.u22.y);
      if (cq < 32) {
        uint2 d;
        d.x = (uint32_t)f2bf(o0) | ((uint32_t)f2bf(o1) << 16);
        d.y = (uint32_t)f2bf(o2) | ((uint32_t)f2bf(o3) << 16);
        *(uint2*)(kT + ((size_t)b * HXW + (size_t)hy * HX + xc) * 128 + ch0) = d;
      } else {
        int c0 = ch0 - 128;
        vt[(c0 + 0) * 35 + px] = f2bf(o0);
        vt[(c0 + 1) * 35 + px] = f2bf(o1);
        vt[(c0 + 2) * 35 + px] = f2bf(o2);
        vt[(c0 + 3) * 35 + px] = f2bf(o3);
      }
    };

#pragma unroll 1
    for (int i = 0; i < 8; i += 2) {
      int pxA = pg + i * 4;
      int pxB = pg + (i + 1) * 4;
      Tap9 ta = load9(pxA);
      Tap9 tb = load9(pxB);
      maskcomp9(ta, pxA);
      maskcomp9(tb, pxB);
    }
    __syncthreads();
    {  // cooperative NCHW store of the V row
      int cv = tid & 127;
      int phx = (tid >> 7) * 16;
      unsigned short* dst = vv + ((size_t)(b * 128 + cv)) * HXW + (size_t)hy * HX + x0 + phx;
      const unsigned short* srcv = vt + cv * 35 + phx;
#pragma unroll
      for (int jj = 0; jj < 4; jj++) {
        uint2 d;
        d.x = (uint32_t)srcv[jj * 4 + 0] | ((uint32_t)srcv[jj * 4 + 1] << 16);
        d.y = (uint32_t)srcv[jj * 4 + 2] | ((uint32_t)srcv[jj * 4 + 3] << 16);
        *(uint2*)(dst + jj * 4) = d;
      }
    }
    __syncthreads();
  }
}

// ---------------------------------------------------------------------------
// 1x1 conv tiled SGEMM (fp32) — small tensors (q path, output projection).
// ---------------------------------------------------------------------------
template <int O>
__global__ __launch_bounds__(256) void conv1_kernel(const float* __restrict__ x,
                                                    const float* __restrict__ w,
                                                    float* __restrict__ y, int HW) {
  constexpr int K = 128;
  constexpr int BK = 32;
  __shared__ __align__(16) float ws_s[BK][64];
  __shared__ __align__(16) float xs_s[BK][64];
  int b = blockIdx.z;
  int o0 = blockIdx.y * 64;
  int p0 = blockIdx.x * 64;
  const float* xb = x + (size_t)b * K * HW;
  int tx = threadIdx.x & 15;
  int ty = threadIdx.x >> 4;
  float acc[4][4] = {};
  int lo = threadIdx.x >> 2;
  int lk = (threadIdx.x & 3) * 8;
  int lc = threadIdx.x >> 3;
  int lp = (threadIdx.x & 7) * 8;

  for (int k0 = 0; k0 < K; k0 += BK) {
    __syncthreads();
    {
      const float* wp = w + (size_t)(o0 + lo) * K + k0 + lk;
      float4 a = *(const float4*)wp;
      float4 bq = *(const float4*)(wp + 4);
      ws_s[lk + 0][lo] = a.x;  ws_s[lk + 1][lo] = a.y;
      ws_s[lk + 2][lo] = a.z;  ws_s[lk + 3][lo] = a.w;
      ws_s[lk + 4][lo] = bq.x; ws_s[lk + 5][lo] = bq.y;
      ws_s[lk + 6][lo] = bq.z; ws_s[lk + 7][lo] = bq.w;
    }
    {
      int p = p0 + lp;
      const float* xp = xb + (size_t)(k0 + lc) * HW;
      float4 a, bq;
      if (p + 7 < HW) {
        a = *(const float4*)(xp + p);
        bq = *(const float4*)(xp + p + 4);
      } else {
        float tv[8];
#pragma unroll
        for (int j = 0; j < 8; j++) tv[j] = (p + j < HW) ? xp[p + j] : 0.0f;
        a = make_float4(tv[0], tv[1], tv[2], tv[3]);
        bq = make_float4(tv[4], tv[5], tv[6], tv[7]);
      }
      *(float4*)&xs_s[lc][lp] = a;
      *(float4*)&xs_s[lc][lp + 4] = bq;
    }
    __syncthreads();
#pragma unroll
    for (int k = 0; k < BK; k++) {
      float4 wv = *(const float4*)&ws_s[k][ty * 4];
      float4 xv = *(const float4*)&xs_s[k][tx * 4];
      acc[0][0] += wv.x * xv.x; acc[0][1] += wv.x * xv.y; acc[0][2] += wv.x * xv.z; acc[0][3] += wv.x * xv.w;
      acc[1][0] += wv.y * xv.x; acc[1][1] += wv.y * xv.y; acc[1][2] += wv.y * xv.z; acc[1][3] += wv.y * xv.w;
      acc[2][0] += wv.z * xv.x; acc[2][1] += wv.z * xv.y; acc[2][2] += wv.z * xv.z; acc[2][3] += wv.z * xv.w;
      acc[3][0] += wv.w * xv.x; acc[3][1] += wv.w * xv.y; acc[3][2] += wv.w * xv.z; acc[3][3] += wv.w * xv.w;
    }
  }
  int p = p0 + tx * 4;
  float* yb = y + (size_t)b * O * HW + (size_t)(o0 + ty * 4) * HW;
#pragma unroll
  for (int j = 0; j < 4; j++) {
    float* yr = yb + (size_t)j * HW + p;
    if (p + 3 < HW) {
      *(float4*)yr = make_float4(acc[j][0], acc[j][1], acc[j][2], acc[j][3]);
    } else {
#pragma unroll
      for (int e = 0; e < 4; e++) if (p + e < HW) yr[e] = acc[j][e];
    }
  }
}

// ---------------------------------------------------------------------------
// MFMA windowed attention, head-pair blocks. 512 thr = 8 waves.
// ---------------------------------------------------------------------------
__global__ __launch_bounds__(512) void attn_mfma_kernel(
    const unsigned short* __restrict__ qn,   // (2,62,62,128) bf16, pre-scaled
    const unsigned short* __restrict__ kT,   // (2,248,248,128) bf16 NHWC
    const unsigned short* __restrict__ vp,   // (2,128,248,248) bf16 NCHW
    float* __restrict__ o) {
  int n = blockIdx.x, hp = blockIdx.y, b = blockIdx.z;
  int wi = n / 10, wj = n % 10;
  int wave = threadIdx.x >> 6;
  int hd = wave & 1, oct = wave >> 1;
  int h = hp * 2 + hd;
  int lane = threadIdx.x & 63;
  int quad = lane >> 4;
  int l15 = lane & 15;
  int y0 = 24 * wi, x0 = 24 * wj;

  __shared__ __align__(16) unsigned short lds[20480];  // 40,960 B
  unsigned short* Pw = lds + wave * 2560;              // [q][40keys] 5KB/wave

  bf16x8 QB[4];
#pragma unroll
  for (int nt = 0; nt < 4; nt++) {
    int qq = nt * 16 + l15;
    int qy = 6 * wi + (qq >> 3), qx = 6 * wj + (qq & 7);
    QB[nt] = __builtin_bit_cast(bf16x8,
        *(const uint4*)(qn + ((size_t)(b * HSW + qy * HS + qx)) * 128 + h * 32 + quad * 8));
  }

  f32x4 Oacc[2][4];
#pragma unroll
  for (int a = 0; a < 2; a++)
#pragma unroll
    for (int c = 0; c < 4; c++) Oacc[a][c] = f32x4{0.f, 0.f, 0.f, 0.f};
  float lsum[4] = {0.f, 0.f, 0.f, 0.f};

  const unsigned short* kb = kT + (size_t)b * HXW * 128 + h * 32;
  const unsigned short* vb = vp + ((size_t)(b * 128 + h * 32)) * HXW;
  const f32x4 zf = {0.f, 0.f, 0.f, 0.f};

#define LOADROW(r, K0, K1, V0, V1)                                              \
  {                                                                             \
    int y = y0 + (r);                                                           \
    const unsigned short* krow = kb + ((size_t)(y * HX + x0)) * 128;            \
    K0 = *(const uint4*)(krow + (size_t)l15 * 128 + quad * 8);                  \
    K1 = *(const uint4*)(krow + (size_t)(16 + l15) * 128 + quad * 8);           \
    const unsigned short* vrow = vb + (size_t)y * HX + x0 + quad * 8;           \
    V0 = *(const uint4*)(vrow + (size_t)l15 * HXW);                             \
    V1 = *(const uint4*)(vrow + (size_t)(16 + l15) * HXW);                      \
  }

  auto compute = [&](uint4 k0, uint4 k1, uint4 v0, uint4 v1) {
    bf16x8 KA0 = __builtin_bit_cast(bf16x8, k0);
    bf16x8 KA1 = __builtin_bit_cast(bf16x8, k1);
    bf16x8 VA0 = __builtin_bit_cast(bf16x8, v0);
    bf16x8 VA1 = __builtin_bit_cast(bf16x8, v1);
    f32x4 S[2][4];
#pragma unroll
    for (int nt = 0; nt < 4; nt++) {
      S[0][nt] = __builtin_amdgcn_mfma_f32_16x16x32_bf16(KA0, QB[nt], zf, 0, 0, 0);
      S[1][nt] = __builtin_amdgcn_mfma_f32_16x16x32_bf16(KA1, QB[nt], zf, 0, 0, 0);
    }
#pragma unroll
    for (int nt = 0; nt < 4; nt++) {
      float pv[2][4];
      float cs = 0.f;
#pragma unroll
      for (int mt = 0; mt < 2; mt++)
#pragma unroll
        for (int r = 0; r < 4; r++) {
          pv[mt][r] = __expf(S[mt][nt][r]);
          cs += pv[mt][r];
        }
      lsum[nt] += cs;
#pragma unroll
      for (int mt = 0; mt < 2; mt++) {
        uint2 d;
        d.x = (uint32_t)f2bf(pv[mt][0]) | ((uint32_t)f2bf(pv[mt][1]) << 16);
        d.y = (uint32_t)f2bf(pv[mt][2]) | ((uint32_t)f2bf(pv[mt][3]) << 16);
        *(uint2*)(Pw + (16 * nt + l15) * 40 + 16 * mt + quad * 4) = d;
      }
    }
#pragma unroll
    for (int nt = 0; nt < 4; nt++) {
      bf16x8 PB = __builtin_bit_cast(bf16x8, *(const uint4*)(Pw + (16 * nt + l15) * 40 + quad * 8));
      Oacc[0][nt] = __builtin_amdgcn_mfma_f32_16x16x32_bf16(VA0, PB, Oacc[0][nt], 0, 0, 0);
      Oacc[1][nt] = __builtin_amdgcn_mfma_f32_16x16x32_bf16(VA1, PB, Oacc[1][nt], 0, 0, 0);
    }
  };

  int rbase = oct * 8;
  uint4 kA0, kA1, vA0, vA1, kB0, kB1, vB0, vB1;
  LOADROW(rbase + 0, kA0, kA1, vA0, vA1);
  LOADROW(rbase + 1, kB0, kB1, vB0, vB1);
#pragma unroll 1
  for (int r = 0; r < 8; r += 2) {
    compute(kA0, kA1, vA0, vA1);
    {
      int rn = (r + 2 < 8) ? (r + 2) : 6;  // clamped, branch-free
      LOADROW(rbase + rn, kA0, kA1, vA0, vA1);
    }
    compute(kB0, kB1, vB0, vB1);
    {
      int rn = (r + 3 < 8) ? (r + 3) : 7;  // clamped, branch-free
      LOADROW(rbase + rn, kB0, kB1, vB0, vB1);
    }
  }
#undef LOADROW

#pragma unroll
  for (int nt = 0; nt < 4; nt++) {
    lsum[nt] += __shfl_xor(lsum[nt], 16, 64);
    lsum[nt] += __shfl_xor(lsum[nt], 32, 64);
  }

  float* mO = (float*)lds;                 // [oct][32ch][64q]  32 KB
  float* mL = (float*)(lds + 16384);       // [oct][64q]
#pragma unroll 1
  for (int p = 0; p < 2; p++) {
    __syncthreads();
    if (hd == p) {
#pragma unroll
      for (int mt = 0; mt < 2; mt++)
#pragma unroll
        for (int nt = 0; nt < 4; nt++)
#pragma unroll
          for (int r = 0; r < 4; r++)
            mO[oct * 2048 + (16 * mt + quad * 4 + r) * 64 + 16 * nt + l15] = Oacc[mt][nt][r];
      if (quad == 0) {
#pragma unroll
        for (int nt = 0; nt < 4; nt++) mL[oct * 64 + nt * 16 + l15] = lsum[nt];
      }
    }
    __syncthreads();
    {
      int q = threadIdx.x & 63;
      int cg = threadIdx.x >> 6;  // 0..7 -> 4 ch each
      float inv = 1.0f / (mL[q] + mL[64 + q] + mL[128 + q] + mL[192 + q]);
      float* ob = o + (((size_t)(b * 100 + n)) * 128 + (hp * 2 + p) * 32 + cg * 4) * 64 + q;
#pragma unroll
      for (int e = 0; e < 4; e++) {
        int ch = cg * 4 + e;
        float s = mO[ch * 64 + q] + mO[2048 + ch * 64 + q] +
                  mO[4096 + ch * 64 + q] + mO[6144 + ch * 64 + q];
        ob[(size_t)e * 64] = s * inv;
      }
    }
  }
}

// ---------------------------------------------------------------------------
// Reverse: scatter-average overlapping 8x8 windows (step 6) into (2,128,62,62)
// ---------------------------------------------------------------------------
__global__ void reverse_kernel(const float* __restrict__ win, float* __restrict__ out) {
  int i = blockIdx.x * 256 + threadIdx.x;
  const int total = 2 * 128 * HSW;
  if (i >= total) return;
  int x = i % HS;
  int t = i / HS;
  int y = t % HS;
  t /= HS;
  int c = t % 128;
  int b = t / 128;
  int wi0 = (y >= 7) ? (y - 2) / 6 : 0;
  int wi1 = min(9, y / 6);
  int wj0 = (x >= 7) ? (x - 2) / 6 : 0;
  int wj1 = min(9, x / 6);
  float s = 0.0f;
  for (int wi = wi0; wi <= wi1; wi++)
    for (int wj = wj0; wj <= wj1; wj++) {
      int di = y - 6 * wi, dj = x - 6 * wj;
      s += win[(((size_t)(b * 100 + wi * 10 + wj)) * 128 + c) * 64 + di * 8 + dj];
    }
  float cnt = (float)((wi1 - wi0 + 1) * (wj1 - wj0 + 1));
  out[i] = s / cnt;
}

// ---------------------------------------------------------------------------
extern "C" void kernel_launch(void* const* d_in, const int* in_sizes, int n_in,
                              void* d_out, int out_size, void* d_ws, size_t ws_size,
                              hipStream_t stream) {
  const float* x      = (const float*)d_in[0];
  const float* sp     = (const float*)d_in[1];
  const float* w_pos  = (const float*)d_in[2];
  const float* b_pos  = (const float*)d_in[3];
  const float* w_q    = (const float*)d_in[4];
  const float* w_qdw  = (const float*)d_in[5];
  const float* w_kv   = (const float*)d_in[6];
  const float* w_kvdw = (const float*)d_in[7];
  const float* w_out  = (const float*)d_in[8];
  float* out = (float*)d_out;

  const size_t N_x   = (size_t)2 * 128 * HXW;  // 15,745,024
  const size_t N_t   = (size_t)2 * 256 * HXW;
  const size_t N_s   = (size_t)2 * 128 * HSW;
  const size_t N_att = (size_t)2 * 100 * 128 * 64;

  float* ws = (float*)d_ws;
  unsigned short* xpb = (unsigned short*)ws;
  unsigned short* kT  = (unsigned short*)ws;
  unsigned short* vv  = kT + N_x;
  unsigned short* tkv = (unsigned short*)(ws + N_x);
  float* att = ws + N_x;
  float* rev = att + N_att;
  float* spp = ws + N_x + N_t / 2;
  float* tq  = spp + N_s;
  unsigned short* qn  = (unsigned short*)(tq + N_s);
  unsigned short* wkb = qn + N_s;              // 32768 ushorts
  (void)ws_size; (void)in_sizes; (void)n_in; (void)out_size;

  // 0. wkb = bf16(w_kv)
  cvt_bf16_kernel<<<128, 256, 0, stream>>>(w_kv, wkb, 256 * 128);
  // 1. xpb = bf16(x + dwconv3(x, w_pos, b_pos))   (bf16 NCHW)
  {
    int total4 = (int)(N_x / 4);
    dwconv4_bf16_kernel<<<(total4 + 255) / 256, 256, 0, stream>>>(x, w_pos, b_pos, xpb, total4);
  }
  // 2. spp = sp + dwconv3(sp, w_pos, b_pos)
  {
    int total = (int)N_s;
    dwconv3_kernel<<<(total + 255) / 256, 256, 0, stream>>>(sp, w_pos, b_pos, spp, 128, HS, HS, total, 1);
  }
  // 3. tq = conv1(spp, w_q)
  {
    int HW = HSW;
    dim3 grid((HW + 63) / 64, 2, 2);
    conv1_kernel<128><<<grid, 256, 0, stream>>>(spp, w_q, tq, HW);
  }
  // 4. qn = bf16_nhwc(dwconv3(tq, w_qdw)) * 32^-0.5
  {
    int total = (int)N_s;
    dwconv_q_kernel<<<(total + 255) / 256, 256, 0, stream>>>(tq, w_qdw, qn, total);
  }
  // 5. tkv = bf16_nhwc(mfma_conv1(xpb, wkb))   (xpb dead after)
  {
    dim3 grid(HXW / 64, 2);
    conv1_kv_mfma_kernel<<<grid, 256, 0, stream>>>(xpb, wkb, tkv);
  }
  // 6. kT (NHWC) + vv (NCHW) = bf16(dwconv3(tkv, w_kvdw))   (overwrites xpb)
  {
    dim3 grid(8, 124, 2);
    dwconv_kv_kernel<<<grid, 256, 0, stream>>>(tkv, w_kvdw, kT, vv);
  }
  // 7. attention -> att (2,100,128,64)
  {
    dim3 grid(100, 2, 2);
    attn_mfma_kernel<<<grid, 512, 0, stream>>>(qn, kT, vv, att);
  }
  // 8. rev = reverse(att)
  {
    int total = (int)N_s;
    reverse_kernel<<<(total + 255) / 256, 256, 0, stream>>>(att, rev);
  }
  // 9. out = conv1(rev, w_out)
  {
    int HW = HSW;
    dim3 grid((HW + 63) / 64, 2, 2);
    conv1_kernel<128><<<grid, 256, 0, stream>>>(rev, w_out, out, HW);
  }
}